// Round 3
// baseline (514.097 us; speedup 1.0000x reference)
//
#include <hip/hip_runtime.h>
#include <hip/hip_bf16.h>

typedef __attribute__((ext_vector_type(8))) short short8;
typedef __attribute__((ext_vector_type(4))) float floatx4;
typedef __attribute__((ext_vector_type(4))) uint uintx4;

#define GN 8192
#define GD 512
#define GEMM_BLOCKS 512     // 8 heads x 64 row-tiles (projection GEMM)

static __device__ __forceinline__ ushort bf16bits(float x) {
  __hip_bfloat16 h = __float2bfloat16(x);
  return *(ushort*)&h;
}
static __device__ __forceinline__ float bf16f(uint u16) {
  return __uint_as_float(u16 << 16);
}

// global->LDS async copy, 16 B per lane (dest = wave-uniform base + lane*16)
typedef __attribute__((address_space(1))) const void g1_void;
typedef __attribute__((address_space(3))) void l3_void;
static __device__ __forceinline__ void gl_lds16(const void* g, void* l) {
  __builtin_amdgcn_global_load_lds((g1_void*)g, (l3_void*)l, 16, 0, 0);
}

// ---------------- Kernel 0: input dtype detector + fp32 bias --------------
__global__ void detect_kernel(const uint* __restrict__ H, const uint* __restrict__ W,
                              const uint* __restrict__ adj, const uint* __restrict__ b,
                              int* __restrict__ flags, float* __restrict__ bias) {
  __shared__ int cH, cW, cA, cB;
  const int t = threadIdx.x;
  if (t == 0) { cH = 0; cW = 0; cA = 0; cB = 0; }
  __syncthreads();
  { const uint e = (H[t] >> 7) & 0xFFu; if (e >= 100u && e <= 140u) atomicAdd(&cH, 1); }
  { const uint e = (W[t] >> 7) & 0xFFu; if (e >= 100u && e <= 140u) atomicAdd(&cW, 1); }
  for (int i = t; i < 4096; i += 256)
    if ((adj[i] & 0xFFFFu) == 0x3F80u) atomicAdd(&cA, 1);
  if (b[t] != 0u) atomicAdd(&cB, 1);
  __syncthreads();
  const int hb = cH > 128, wb = cW > 128, ab = cA > 0;
  if (t == 0) { flags[0] = hb; flags[1] = wb; flags[2] = ab; }
  if (cB == 0) {
    bias[t] = 0.0f; bias[t + 256] = 0.0f;
  } else if (wb) {
    const ushort* bs = (const ushort*)b;
    bias[t] = bf16f(bs[t]); bias[t + 256] = bf16f(bs[t + 256]);
  } else {
    const float* bf = (const float*)b;
    bias[t] = bf[t]; bias[t + 256] = bf[t + 256];
  }
}

// ---------------- Kernel 1: projection GEMM -> HPt (transposed) ------------
// HPt[col][row] = bf16( (H @ W_head)[row][col] ), col = head*64 + e.
// 128x64 tile per block, 16x16x32 bf16 MFMA (verified fragment mapping).
#define BM 128
#define BN 64
#define BK 64
#define LDK 72   // padded LDS row stride (bf16 elems) — breaks 32-bank stride

#define SMEM_BYTES (BM * LDK * 2 + BN * LDK * 2)   // 27648

__global__ __launch_bounds__(256) void proj_kernel(
    const void* __restrict__ Hv, const void* __restrict__ Wv,
    ushort* __restrict__ HPt, const int* __restrict__ flags) {
  __shared__ __align__(16) unsigned char smem[SMEM_BYTES];
  ushort* sA = (ushort*)smem;                    // [BM][LDK]
  ushort* sB = (ushort*)(smem + BM * LDK * 2);   // [BN][LDK]
  const int tid = threadIdx.x;
  const int hb = flags[0];
  const int wb = flags[1];
  const int bn = blockIdx.x & 7;     // head
  const int bm = blockIdx.x >> 3;    // row tile
  const int m0 = bm * BM;
  const int lane = tid & 63;
  const int w = tid >> 6;
  const int wr = w >> 1, wc = w & 1;
  const int l15 = lane & 15, q = lane >> 4;

  floatx4 acc[4][2];
#pragma unroll
  for (int i = 0; i < 4; i++)
#pragma unroll
    for (int j = 0; j < 2; j++) acc[i][j] = (floatx4)0.0f;

  for (int k0 = 0; k0 < GD; k0 += BK) {
    __syncthreads();
    // ---- stage A (128 x 64) ----
    if (hb) {
      const ushort* H16 = (const ushort*)Hv;
      const int r = tid >> 3;
      const int kc = (tid & 7) * 8;
#pragma unroll
      for (int p = 0; p < 4; p++) {
        const int row = r + p * 32;
        const uint4 v = *(const uint4*)(H16 + (size_t)(m0 + row) * GD + k0 + kc);
        *(uint4*)(sA + row * LDK + kc) = v;
      }
    } else {
      const float* H32 = (const float*)Hv;
      const int r0 = tid >> 4;
      const int kc = (tid & 15) * 4;
#pragma unroll
      for (int p = 0; p < 8; p++) {
        const int row = r0 + p * 16;
        const float4 v = *(const float4*)(H32 + (size_t)(m0 + row) * GD + k0 + kc);
        ushort4 o;
        o.x = bf16bits(v.x); o.y = bf16bits(v.y);
        o.z = bf16bits(v.z); o.w = bf16bits(v.w);
        *(ushort4*)(sA + row * LDK + kc) = o;
      }
    }
    // ---- stage B: W[h][k][e] -> sB[e][k] ----
    if (wb) {
      const ushort* Wh = (const ushort*)Wv + (size_t)bn * (512 * 64);
      const int kk = tid >> 3;
      const int e0 = (tid & 7) * 8;
#pragma unroll
      for (int p = 0; p < 2; p++) {
        const int k = kk + p * 32;
        const uint4 v = *(const uint4*)(Wh + (size_t)(k0 + k) * 64 + e0);
        const ushort* pv = (const ushort*)&v;
#pragma unroll
        for (int j = 0; j < 8; j++) sB[(e0 + j) * LDK + k] = pv[j];
      }
    } else {
      const float* Wh = (const float*)Wv + (size_t)bn * (512 * 64);
      const int kk = tid >> 4;
      const int e0 = (tid & 15) * 4;
#pragma unroll
      for (int p = 0; p < 4; p++) {
        const int k = kk + p * 16;
        const float4 v = *(const float4*)(Wh + (size_t)(k0 + k) * 64 + e0);
        sB[(e0 + 0) * LDK + k] = bf16bits(v.x);
        sB[(e0 + 1) * LDK + k] = bf16bits(v.y);
        sB[(e0 + 2) * LDK + k] = bf16bits(v.z);
        sB[(e0 + 3) * LDK + k] = bf16bits(v.w);
      }
    }
    __syncthreads();
    // ---- MFMA ----
#pragma unroll
    for (int kq = 0; kq < 2; kq++) {
      short8 af[4], bfv[2];
#pragma unroll
      for (int mt = 0; mt < 4; mt++)
        af[mt] = *(const short8*)(sA + (wr * 64 + mt * 16 + l15) * LDK + kq * 32 + q * 8);
#pragma unroll
      for (int ct = 0; ct < 2; ct++)
        bfv[ct] = *(const short8*)(sB + (wc * 32 + ct * 16 + l15) * LDK + kq * 32 + q * 8);
#pragma unroll
      for (int mt = 0; mt < 4; mt++)
#pragma unroll
        for (int ct = 0; ct < 2; ct++)
          acc[mt][ct] = __builtin_amdgcn_mfma_f32_16x16x32_bf16(
              af[mt], bfv[ct], acc[mt][ct], 0, 0, 0);
    }
  }
  // epilogue -> HPt[col][row]; D frag: row=(lane>>4)*4+r, col=lane&15.
  // 4 consecutive rows per fragment pack into one ushort4 store.
#pragma unroll
  for (int mt = 0; mt < 4; mt++)
#pragma unroll
    for (int ct = 0; ct < 2; ct++) {
      const int col = bn * 64 + wc * 32 + ct * 16 + l15;
      const int rowb = m0 + wr * 64 + mt * 16 + q * 4;
      ushort4 o;
      o.x = bf16bits(acc[mt][ct][0]);
      o.y = bf16bits(acc[mt][ct][1]);
      o.z = bf16bits(acc[mt][ct][2]);
      o.w = bf16bits(acc[mt][ct][3]);
      *(ushort4*)(HPt + (size_t)col * GN + rowb) = o;
    }
}

// ---------------- Kernel 2: aggregation GEMM (dense, bf16 MFMA) ------------
// partial[kch][n][e] = sum_{m in kchunk} adj[n][m] * HPt[e][m]   (fp32)
// BM=64 rows x BN=512 cols per block, K-chunk 2048, 512 blocks x 512 thr
// -> 2 blocks/CU (LDS 74.75 KB). kch = bid & 3: with XCD = bid % 8 each XCD
// serves exactly one kchunk -> its 2 MB HPt slice stays L2-resident.
//
// sB must stay LINEAR for global_load_lds, so bank-conflict fix is the
// both-sides swizzle (rule 21): per-lane pre-swizzled GLOBAL source
// (chunk ^= row&7, 16B granules) + same XOR on the ds_read_b128 address.
#define ABM 64
#define ABK 64
#define AKCH 2048
#define ALDA 72   // padded sA stride (conflict-free fragment reads)

__global__ __launch_bounds__(512) void agg_kernel(
    const void* __restrict__ adjv, const ushort* __restrict__ HPt,
    float* __restrict__ pbuf, const int* __restrict__ flags) {
  __shared__ __align__(16) ushort sA[ABM * ALDA];   // 9216 B
  __shared__ __align__(16) ushort sB[GD * 64];      // 65536 B, [e][64k] linear
  const int ab = flags[2];
  const int bid = blockIdx.x;
  const int kch = bid & 3;
  const int m0 = (bid >> 2) * ABM;
  const size_t kb = (size_t)kch * AKCH;
  const int tid = threadIdx.x;
  const int lane = tid & 63, w = tid >> 6;
  const int l15 = lane & 15, q = lane >> 4;

  floatx4 acc[4][4];
#pragma unroll
  for (int i = 0; i < 4; i++)
#pragma unroll
    for (int j = 0; j < 4; j++) acc[i][j] = (floatx4)0.0f;

  // B staging: round p, wave w covers sB rows [p*64+w*8, +8); lane L ->
  // row +(L>>3), LDS slot (L&7) (linear dest). Source chunk is pre-swizzled:
  // c_g = (L&7) ^ (L>>3)  (row&7 == L>>3 here), so LDS slot s of row e holds
  // global chunk s ^ (e&7).
  const int brow = lane >> 3;
  const int bkc = ((lane & 7) ^ brow) * 8;   // swizzled bf16 elem offset

  for (int k0 = 0; k0 < AKCH; k0 += ABK) {
    __syncthreads();
    // ---- stage B: HPt[e][kb+k0 .. +64) -> sB (swizzled), global_load_lds --
#pragma unroll
    for (int p = 0; p < 8; p++) {
      const int e = p * 64 + w * 8 + brow;
      gl_lds16(HPt + (size_t)e * GN + kb + k0 + bkc,
               sB + (size_t)(p * 64 + w * 8) * 64);
    }
    // ---- stage A: adj[m0..+64)[kb+k0..+64) -> sA bf16 (nontemporal) ----
    if (ab) {
      const ushort* adj16 = (const ushort*)adjv;
      const int n = tid >> 3;
      const int kc = (tid & 7) * 8;
      const uintx4 v = __builtin_nontemporal_load(
          (const uintx4*)(adj16 + (size_t)(m0 + n) * GN + kb + k0 + kc));
      *(uintx4*)(sA + n * ALDA + kc) = v;
    } else {
      const float* adj32 = (const float*)adjv;
      const int n = tid >> 3;
      const int kc = (tid & 7) * 8;
      const float* src = adj32 + (size_t)(m0 + n) * GN + kb + k0 + kc;
      const floatx4 v0 = __builtin_nontemporal_load((const floatx4*)src);
      const floatx4 v1 = __builtin_nontemporal_load((const floatx4*)(src + 4));
      ushort4 o0, o1;
      o0.x = bf16bits(v0.x); o0.y = bf16bits(v0.y);
      o0.z = bf16bits(v0.z); o0.w = bf16bits(v0.w);
      o1.x = bf16bits(v1.x); o1.y = bf16bits(v1.y);
      o1.z = bf16bits(v1.z); o1.w = bf16bits(v1.w);
      *(ushort4*)(sA + n * ALDA + kc) = o0;
      *(ushort4*)(sA + n * ALDA + kc + 4) = o1;
    }
    __syncthreads();
    // ---- MFMA: wave w owns cols [w*64, +64) ----
#pragma unroll
    for (int kq = 0; kq < 2; kq++) {
      short8 af[4], bfr[4];
#pragma unroll
      for (int mt = 0; mt < 4; mt++)
        af[mt] = *(const short8*)(sA + (mt * 16 + l15) * ALDA + kq * 32 + q * 8);
#pragma unroll
      for (int ct = 0; ct < 4; ct++) {
        const int r = w * 64 + ct * 16 + l15;
        const int slot = (kq * 4 + q) ^ (l15 & 7);   // un-swizzle on read
        bfr[ct] = *(const short8*)(sB + r * 64 + slot * 8);
      }
#pragma unroll
      for (int mt = 0; mt < 4; mt++)
#pragma unroll
        for (int ct = 0; ct < 4; ct++)
          acc[mt][ct] = __builtin_amdgcn_mfma_f32_16x16x32_bf16(
              af[mt], bfr[ct], acc[mt][ct], 0, 0, 0);
    }
  }
  // ---- epilogue: fp32 partials (nontemporal; keep L2 for HPt) ----
  float* pb = pbuf + (size_t)kch * ((size_t)GN * GD);
#pragma unroll
  for (int mt = 0; mt < 4; mt++)
#pragma unroll
    for (int ct = 0; ct < 4; ct++) {
      const int col = w * 64 + ct * 16 + l15;
      const int rowb = m0 + mt * 16 + q * 4;
#pragma unroll
      for (int r = 0; r < 4; r++)
        __builtin_nontemporal_store(
            acc[mt][ct][r], pb + (size_t)(rowb + r) * GD + col);
    }
}

// ---------------- Kernel 3: combine 4 partials + bias ----------------------
__global__ __launch_bounds__(256) void combine_kernel(
    const float* __restrict__ pbuf, const float* __restrict__ bias,
    float* __restrict__ out) {
  const int i = blockIdx.x * 256 + threadIdx.x;       // float4 index, 1M total
  const size_t stride = (size_t)GN * GD / 4;          // float4s per partial
  floatx4 s = __builtin_nontemporal_load((const floatx4*)pbuf + i);
#pragma unroll
  for (int j = 1; j < 4; j++) {
    const floatx4 a = __builtin_nontemporal_load(
        (const floatx4*)pbuf + j * stride + i);
    s.x += a.x; s.y += a.y; s.z += a.z; s.w += a.w;
  }
  const floatx4 bb = *((const floatx4*)bias + (i & 127));
  floatx4 o;
  o.x = s.x + bb.x; o.y = s.y + bb.y; o.z = s.z + bb.z; o.w = s.w + bb.w;
  __builtin_nontemporal_store(o, (floatx4*)out + i);
}

extern "C" void kernel_launch(void* const* d_in, const int* in_sizes, int n_in,
                              void* d_out, int out_size, void* d_ws, size_t ws_size,
                              hipStream_t stream) {
  // identify inputs by element count (order-proof)
  const void *H = d_in[0], *adj = d_in[1], *W = d_in[2], *b = d_in[3];
  for (int i = 0; i < n_in; i++) {
    const int s = in_sizes[i];
    if (s == GN * GN) adj = d_in[i];
    else if (s == GN * GD) H = d_in[i];
    else if (s == 8 * 512 * 64) W = d_in[i];
    else if (s == 512) b = d_in[i];
  }
  float* out = (float*)d_out;                     // (8192, 512) fp32

  char* ws = (char*)d_ws;
  ushort* HPt  = (ushort*)ws;                                   // 8 MB bf16 (512 x 8192)
  float*  bias = (float*)(ws + (size_t)GN * GD * 2);            // 2 KB
  int*    flags= (int*)(ws + (size_t)GN * GD * 2 + 4096);       // 16 B
  float*  pbuf = (float*)(ws + (size_t)16 * 1024 * 1024);       // 4 x 16 MB fp32

  detect_kernel<<<1, 256, 0, stream>>>((const uint*)H, (const uint*)W,
                                       (const uint*)adj, (const uint*)b,
                                       flags, bias);
  proj_kernel<<<GEMM_BLOCKS, 256, 0, stream>>>(H, W, HPt, flags);
  agg_kernel<<<512, 512, 0, stream>>>(adj, HPt, pbuf, flags);
  combine_kernel<<<4096, 256, 0, stream>>>(pbuf, bias, out);
}

// Round 4
// 501.048 us; speedup vs baseline: 1.0260x; 1.0260x over previous
//
#include <hip/hip_runtime.h>
#include <hip/hip_bf16.h>

typedef __attribute__((ext_vector_type(8))) short short8;
typedef __attribute__((ext_vector_type(4))) float floatx4;
typedef __attribute__((ext_vector_type(4))) uint uintx4;

#define GN 8192
#define GD 512
#define GEMM_BLOCKS 512     // 8 heads x 64 row-tiles (projection GEMM)

static __device__ __forceinline__ ushort bf16bits(float x) {
  __hip_bfloat16 h = __float2bfloat16(x);
  return *(ushort*)&h;
}
static __device__ __forceinline__ float bf16f(uint u16) {
  return __uint_as_float(u16 << 16);
}

// global->LDS async copy, 16 B per lane (dest = wave-uniform base + lane*16)
typedef __attribute__((address_space(1))) const void g1_void;
typedef __attribute__((address_space(3))) void l3_void;
static __device__ __forceinline__ void gl_lds16(const void* g, void* l) {
  __builtin_amdgcn_global_load_lds((g1_void*)g, (l3_void*)l, 16, 0, 0);
}

// ---------------- Kernel 0: input dtype detector + fp32 bias --------------
__global__ void detect_kernel(const uint* __restrict__ H, const uint* __restrict__ W,
                              const uint* __restrict__ adj, const uint* __restrict__ b,
                              int* __restrict__ flags, float* __restrict__ bias) {
  __shared__ int cH, cW, cA, cB;
  const int t = threadIdx.x;
  if (t == 0) { cH = 0; cW = 0; cA = 0; cB = 0; }
  __syncthreads();
  { const uint e = (H[t] >> 7) & 0xFFu; if (e >= 100u && e <= 140u) atomicAdd(&cH, 1); }
  { const uint e = (W[t] >> 7) & 0xFFu; if (e >= 100u && e <= 140u) atomicAdd(&cW, 1); }
  for (int i = t; i < 4096; i += 256)
    if ((adj[i] & 0xFFFFu) == 0x3F80u) atomicAdd(&cA, 1);
  if (b[t] != 0u) atomicAdd(&cB, 1);
  __syncthreads();
  const int hb = cH > 128, wb = cW > 128, ab = cA > 0;
  if (t == 0) { flags[0] = hb; flags[1] = wb; flags[2] = ab; }
  if (cB == 0) {
    bias[t] = 0.0f; bias[t + 256] = 0.0f;
  } else if (wb) {
    const ushort* bs = (const ushort*)b;
    bias[t] = bf16f(bs[t]); bias[t + 256] = bf16f(bs[t + 256]);
  } else {
    const float* bf = (const float*)b;
    bias[t] = bf[t]; bias[t + 256] = bf[t + 256];
  }
}

// ---------------- Kernel 1: projection GEMM -> HPt (transposed) ------------
// HPt[col][row] = bf16( (H @ W_head)[row][col] ), col = head*64 + e.
// 128x64 tile per block, 16x16x32 bf16 MFMA (verified fragment mapping).
#define BM 128
#define BN 64
#define BK 64
#define LDK 72   // padded LDS row stride (bf16 elems) — breaks 32-bank stride

#define SMEM_BYTES (BM * LDK * 2 + BN * LDK * 2)   // 27648

__global__ __launch_bounds__(256) void proj_kernel(
    const void* __restrict__ Hv, const void* __restrict__ Wv,
    ushort* __restrict__ HPt, const int* __restrict__ flags) {
  __shared__ __align__(16) unsigned char smem[SMEM_BYTES];
  ushort* sA = (ushort*)smem;                    // [BM][LDK]
  ushort* sB = (ushort*)(smem + BM * LDK * 2);   // [BN][LDK]
  const int tid = threadIdx.x;
  const int hb = flags[0];
  const int wb = flags[1];
  const int bn = blockIdx.x & 7;     // head
  const int bm = blockIdx.x >> 3;    // row tile
  const int m0 = bm * BM;
  const int lane = tid & 63;
  const int w = tid >> 6;
  const int wr = w >> 1, wc = w & 1;
  const int l15 = lane & 15, q = lane >> 4;

  floatx4 acc[4][2];
#pragma unroll
  for (int i = 0; i < 4; i++)
#pragma unroll
    for (int j = 0; j < 2; j++) acc[i][j] = (floatx4)0.0f;

  for (int k0 = 0; k0 < GD; k0 += BK) {
    __syncthreads();
    // ---- stage A (128 x 64) ----
    if (hb) {
      const ushort* H16 = (const ushort*)Hv;
      const int r = tid >> 3;
      const int kc = (tid & 7) * 8;
#pragma unroll
      for (int p = 0; p < 4; p++) {
        const int row = r + p * 32;
        const uint4 v = *(const uint4*)(H16 + (size_t)(m0 + row) * GD + k0 + kc);
        *(uint4*)(sA + row * LDK + kc) = v;
      }
    } else {
      const float* H32 = (const float*)Hv;
      const int r0 = tid >> 4;
      const int kc = (tid & 15) * 4;
#pragma unroll
      for (int p = 0; p < 8; p++) {
        const int row = r0 + p * 16;
        const float4 v = *(const float4*)(H32 + (size_t)(m0 + row) * GD + k0 + kc);
        ushort4 o;
        o.x = bf16bits(v.x); o.y = bf16bits(v.y);
        o.z = bf16bits(v.z); o.w = bf16bits(v.w);
        *(ushort4*)(sA + row * LDK + kc) = o;
      }
    }
    // ---- stage B: W[h][k][e] -> sB[e][k] ----
    if (wb) {
      const ushort* Wh = (const ushort*)Wv + (size_t)bn * (512 * 64);
      const int kk = tid >> 3;
      const int e0 = (tid & 7) * 8;
#pragma unroll
      for (int p = 0; p < 2; p++) {
        const int k = kk + p * 32;
        const uint4 v = *(const uint4*)(Wh + (size_t)(k0 + k) * 64 + e0);
        const ushort* pv = (const ushort*)&v;
#pragma unroll
        for (int j = 0; j < 8; j++) sB[(e0 + j) * LDK + k] = pv[j];
      }
    } else {
      const float* Wh = (const float*)Wv + (size_t)bn * (512 * 64);
      const int kk = tid >> 4;
      const int e0 = (tid & 15) * 4;
#pragma unroll
      for (int p = 0; p < 4; p++) {
        const int k = kk + p * 16;
        const float4 v = *(const float4*)(Wh + (size_t)(k0 + k) * 64 + e0);
        sB[(e0 + 0) * LDK + k] = bf16bits(v.x);
        sB[(e0 + 1) * LDK + k] = bf16bits(v.y);
        sB[(e0 + 2) * LDK + k] = bf16bits(v.z);
        sB[(e0 + 3) * LDK + k] = bf16bits(v.w);
      }
    }
    __syncthreads();
    // ---- MFMA ----
#pragma unroll
    for (int kq = 0; kq < 2; kq++) {
      short8 af[4], bfv[2];
#pragma unroll
      for (int mt = 0; mt < 4; mt++)
        af[mt] = *(const short8*)(sA + (wr * 64 + mt * 16 + l15) * LDK + kq * 32 + q * 8);
#pragma unroll
      for (int ct = 0; ct < 2; ct++)
        bfv[ct] = *(const short8*)(sB + (wc * 32 + ct * 16 + l15) * LDK + kq * 32 + q * 8);
#pragma unroll
      for (int mt = 0; mt < 4; mt++)
#pragma unroll
        for (int ct = 0; ct < 2; ct++)
          acc[mt][ct] = __builtin_amdgcn_mfma_f32_16x16x32_bf16(
              af[mt], bfv[ct], acc[mt][ct], 0, 0, 0);
    }
  }
  // epilogue -> HPt[col][row]; D frag: row=(lane>>4)*4+r, col=lane&15.
  // 4 consecutive rows per fragment pack into one ushort4 store.
#pragma unroll
  for (int mt = 0; mt < 4; mt++)
#pragma unroll
    for (int ct = 0; ct < 2; ct++) {
      const int col = bn * 64 + wc * 32 + ct * 16 + l15;
      const int rowb = m0 + wr * 64 + mt * 16 + q * 4;
      ushort4 o;
      o.x = bf16bits(acc[mt][ct][0]);
      o.y = bf16bits(acc[mt][ct][1]);
      o.z = bf16bits(acc[mt][ct][2]);
      o.w = bf16bits(acc[mt][ct][3]);
      *(ushort4*)(HPt + (size_t)col * GN + rowb) = o;
    }
}

// ---------------- Kernel 2: aggregation GEMM, 1-deep pipelined -------------
// partial[kch][n][e] = sum_{m in kchunk} adj[n][m] * HPt[e][m]   (fp32)
// BM=64 x BN=512 per block, K-chunk 4096 (Ksplit2), grid 256 x 512 thr =
// 1 block/CU (by design: BN=512 so adj is read exactly once; latency hiding
// comes from the in-block pipeline, not occupancy).
// kch = bid & 1 -> XCD parity; each XCD's 4 MB HPt k-slice stays L2-resident.
//
// Pipeline (T3-minimum + T14 split): sB double-buffered; per K-step issue
// B(k+1) global_load_lds into sB[nxt] and A(k+1) global->reg loads BEFORE
// the MFMA phase; __syncthreads() after MFMA drains them (compiler emits
// vmcnt(0) before s_barrier); convert+ds_write A(k+1) after the barrier.
// sB keeps the round-3 verified both-sides XOR swizzle (rule 21).
#define ABM 64
#define ABK 64
#define AKCH 4096
#define ANT (AKCH / ABK)   // 64 K-steps
#define ALDA 72            // padded sA stride

__global__ __launch_bounds__(512, 2) void agg_kernel(
    const void* __restrict__ adjv, const ushort* __restrict__ HPt,
    float* __restrict__ pbuf, const int* __restrict__ flags) {
  __shared__ __align__(16) ushort sA[ABM * ALDA];   // 9216 B
  __shared__ __align__(16) ushort sB[2][GD * 64];   // 2 x 65536 B (dbuf)
  const int ab = flags[2];
  const int bid = blockIdx.x;
  const int kch = bid & 1;
  const int m0 = (bid >> 1) * ABM;
  const size_t kb = (size_t)kch * AKCH;
  const int tid = threadIdx.x;
  const int lane = tid & 63, w = tid >> 6;
  const int l15 = lane & 15, q = lane >> 4;

  // B staging: wave-uniform linear LDS dest; per-lane pre-swizzled global src
  const int brow = lane >> 3;                 // 0..7
  const int bkc = ((lane & 7) ^ brow) * 8;    // swizzled bf16 elem offset
  // A staging coords: thread -> 8 fp32 (or 8 bf16) of one adj row
  const int an = tid >> 3;                    // row 0..63
  const int akc = (tid & 7) * 8;              // col elem offset

  const ushort* adj16 = (const ushort*)adjv;
  const float* adj32 = (const float*)adjv;

  floatx4 acc[4][4];
#pragma unroll
  for (int i = 0; i < 4; i++)
#pragma unroll
    for (int j = 0; j < 4; j++) acc[i][j] = (floatx4)0.0f;

  // prefetch registers for A(k+1)
  floatx4 a0, a1;
  uintx4 au;

#define STAGE_B(K0, BUF)                                                  \
  {                                                                       \
    _Pragma("unroll")                                                     \
    for (int p = 0; p < 8; p++) {                                         \
      const int e = p * 64 + w * 8 + brow;                                \
      gl_lds16(HPt + (size_t)e * GN + kb + (K0) + bkc,                    \
               &sB[BUF][(p * 64 + w * 8) * 64]);                          \
    }                                                                     \
  }

#define LOAD_A(K0)                                                        \
  {                                                                       \
    if (ab) {                                                             \
      au = __builtin_nontemporal_load(                                    \
          (const uintx4*)(adj16 + (size_t)(m0 + an) * GN + kb + (K0) + akc)); \
    } else {                                                              \
      const float* src = adj32 + (size_t)(m0 + an) * GN + kb + (K0) + akc;\
      a0 = __builtin_nontemporal_load((const floatx4*)src);               \
      a1 = __builtin_nontemporal_load((const floatx4*)(src + 4));         \
    }                                                                     \
  }

#define WRITE_A()                                                         \
  {                                                                       \
    if (ab) {                                                             \
      *(uintx4*)(sA + an * ALDA + akc) = au;                              \
    } else {                                                              \
      ushort4 o0, o1;                                                     \
      o0.x = bf16bits(a0.x); o0.y = bf16bits(a0.y);                       \
      o0.z = bf16bits(a0.z); o0.w = bf16bits(a0.w);                       \
      o1.x = bf16bits(a1.x); o1.y = bf16bits(a1.y);                       \
      o1.z = bf16bits(a1.z); o1.w = bf16bits(a1.w);                       \
      *(ushort4*)(sA + an * ALDA + akc) = o0;                             \
      *(ushort4*)(sA + an * ALDA + akc + 4) = o1;                        \
    }                                                                     \
  }

  // ---- prologue: stage B(0) -> sB[0], A(0) -> regs -> sA ----
  STAGE_B(0, 0)
  LOAD_A(0)
  WRITE_A()          // compiler auto-waits vmcnt for a0/a1/au
  __syncthreads();   // drains gl_lds vmcnt + ds_writes; all buffers ready

  int cur = 0;
  for (int k = 0; k < ANT; ++k) {
    const int k1 = (k + 1) * ABK;
    if (k + 1 < ANT) {
      STAGE_B(k1, cur ^ 1)   // into the other buffer — no dep on this step
      LOAD_A(k1)             // HBM latency hides under MFMA phase below
    }
    // ---- MFMA over sA, sB[cur]: wave w owns cols [w*64, +64) ----
#pragma unroll
    for (int kq = 0; kq < 2; kq++) {
      short8 af[4], bfr[4];
#pragma unroll
      for (int mt = 0; mt < 4; mt++)
        af[mt] = *(const short8*)(sA + (mt * 16 + l15) * ALDA + kq * 32 + q * 8);
#pragma unroll
      for (int ct = 0; ct < 4; ct++) {
        const int r = w * 64 + ct * 16 + l15;
        const int slot = (kq * 4 + q) ^ (l15 & 7);   // un-swizzle on read
        bfr[ct] = *(const short8*)(&sB[cur][r * 64 + slot * 8]);
      }
#pragma unroll
      for (int mt = 0; mt < 4; mt++)
#pragma unroll
        for (int ct = 0; ct < 4; ct++)
          acc[mt][ct] = __builtin_amdgcn_mfma_f32_16x16x32_bf16(
              af[mt], bfr[ct], acc[mt][ct], 0, 0, 0);
    }
    __syncthreads();          // drains sA reads + prefetch loads (vmcnt(0))
    if (k + 1 < ANT) WRITE_A()
    __syncthreads();          // sA(k+1) visible; sB[cur^1] already complete
    cur ^= 1;
  }

  // ---- epilogue: fp32 partials (nontemporal; keep L2 for HPt) ----
  float* pb = pbuf + (size_t)kch * ((size_t)GN * GD);
#pragma unroll
  for (int mt = 0; mt < 4; mt++)
#pragma unroll
    for (int ct = 0; ct < 4; ct++) {
      const int col = w * 64 + ct * 16 + l15;
      const int rowb = m0 + mt * 16 + q * 4;
#pragma unroll
      for (int r = 0; r < 4; r++)
        __builtin_nontemporal_store(
            acc[mt][ct][r], pb + (size_t)(rowb + r) * GD + col);
    }
#undef STAGE_B
#undef LOAD_A
#undef WRITE_A
}

// ---------------- Kernel 3: combine 2 partials + bias ----------------------
__global__ __launch_bounds__(256) void combine_kernel(
    const float* __restrict__ pbuf, const float* __restrict__ bias,
    float* __restrict__ out) {
  const int i = blockIdx.x * 256 + threadIdx.x;       // float4 index, 1M total
  const size_t stride = (size_t)GN * GD / 4;          // float4s per partial
  const floatx4 p0 = __builtin_nontemporal_load((const floatx4*)pbuf + i);
  const floatx4 p1 = __builtin_nontemporal_load((const floatx4*)pbuf + stride + i);
  const floatx4 bb = *((const floatx4*)bias + (i & 127));
  floatx4 o;
  o.x = p0.x + p1.x + bb.x;
  o.y = p0.y + p1.y + bb.y;
  o.z = p0.z + p1.z + bb.z;
  o.w = p0.w + p1.w + bb.w;
  __builtin_nontemporal_store(o, (floatx4*)out + i);
}

extern "C" void kernel_launch(void* const* d_in, const int* in_sizes, int n_in,
                              void* d_out, int out_size, void* d_ws, size_t ws_size,
                              hipStream_t stream) {
  // identify inputs by element count (order-proof)
  const void *H = d_in[0], *adj = d_in[1], *W = d_in[2], *b = d_in[3];
  for (int i = 0; i < n_in; i++) {
    const int s = in_sizes[i];
    if (s == GN * GN) adj = d_in[i];
    else if (s == GN * GD) H = d_in[i];
    else if (s == 8 * 512 * 64) W = d_in[i];
    else if (s == 512) b = d_in[i];
  }
  float* out = (float*)d_out;                     // (8192, 512) fp32

  char* ws = (char*)d_ws;
  ushort* HPt  = (ushort*)ws;                                   // 8 MB bf16 (512 x 8192)
  float*  bias = (float*)(ws + (size_t)GN * GD * 2);            // 2 KB
  int*    flags= (int*)(ws + (size_t)GN * GD * 2 + 4096);       // 16 B
  float*  pbuf = (float*)(ws + (size_t)16 * 1024 * 1024);       // 2 x 16 MB fp32

  detect_kernel<<<1, 256, 0, stream>>>((const uint*)H, (const uint*)W,
                                       (const uint*)adj, (const uint*)b,
                                       flags, bias);
  proj_kernel<<<GEMM_BLOCKS, 256, 0, stream>>>(H, W, HPt, flags);
  agg_kernel<<<256, 512, 0, stream>>>(adj, HPt, pbuf, flags);
  combine_kernel<<<4096, 256, 0, stream>>>(pbuf, bias, out);
}